// Round 12
// baseline (57.282 us; speedup 1.0000x reference)
//
#include <hip/hip_runtime.h>
#include <math.h>

#define LOG2E 1.4426950408889634f
typedef __attribute__((ext_vector_type(2))) _Float16 h2v;
typedef __attribute__((ext_vector_type(8))) _Float16 f16x8;
typedef __attribute__((ext_vector_type(4))) float f32x4;

static __device__ __forceinline__ unsigned pkrtz_u32(float lo, float hi) {
  auto p = __builtin_amdgcn_cvt_pkrtz(lo, hi);
  unsigned u; __builtin_memcpy(&u, &p, 4); return u;
}
static __device__ __forceinline__ h2v habs2(h2v x) {
  unsigned u; __builtin_memcpy(&u, &x, 4);
  u &= 0x7FFF7FFFu;
  h2v r; __builtin_memcpy(&r, &u, 4); return r;
}
static __device__ __forceinline__ h2v u2h(unsigned u) {
  h2v r; __builtin_memcpy(&r, &u, 4); return r;
}

// s[i,j] = Ci + Dj + sum_h ab_h*|hq_ih + hkb_jh|, ab=0.05a, Dj=0.075(a.hkb_j)
// Ci per-row -> cancels in softmax -> dropped.
// khT4: [b][h4][j] uint4 = f16 pairs of h=8*h4..8*h4+7 (bias folded).
// hq2: [row][h2] u32 f16 pairs. abd2: [h2] u32 pairs of 0.05a.
// vfrag: [b][kstep][ntile][lane] uint4 — V in MFMA B-frag order.

// ---------------- Kernel A: prep (blocks 0-127) + vpack (blocks 128-255) ------
__global__ __launch_bounds__(256) void prep_kernel(
    const float* __restrict__ qs, const float* __restrict__ ks,
    const float* __restrict__ vs,
    const float* __restrict__ W, const float* __restrict__ bias,
    const float* __restrict__ a,
    unsigned* __restrict__ hq2, uint4* __restrict__ khT4,
    float* __restrict__ Dj, unsigned* __restrict__ abd2,
    uint4* __restrict__ vfrag) {
  __shared__ __align__(16) float wcomb[64][68];
  __shared__ __align__(16) float xin[64][68];
  const int blk = blockIdx.x;
  const int t = threadIdx.x;

  if (blk >= 128) {  // ---- vpack: V -> MFMA B-fragment f16 layout ----
    const int unit = blk - 128;             // b = unit>>5, kstep = unit&31
    const int b = unit >> 5, kstep = unit & 31;
    const int lane = t & 63, ntile = t >> 6;
    const int j0 = kstep * 32 + (lane >> 4) * 8;
    const int d = ntile * 16 + (lane & 15);
    const float* vb = vs + b * 1024 * 64;
    unsigned pr[4];
#pragma unroll
    for (int i = 0; i < 4; ++i)
      pr[i] = pkrtz_u32(vb[(j0 + 2 * i) * 64 + d], vb[(j0 + 2 * i + 1) * 64 + d]);
    vfrag[((b * 32 + kstep) * 4 + ntile) * 64 + lane] =
        make_uint4(pr[0], pr[1], pr[2], pr[3]);
    return;
  }

  const bool qpart = blk < 64;
  const int r0 = (qpart ? blk : blk - 64) * 64;
  const float* src = qpart ? qs : ks;
  if (blk == 0 && t < 32)
    abd2[t] = pkrtz_u32(0.05f * a[2 * t], 0.05f * a[2 * t + 1]);
  for (int rep = 0; rep < 16; ++rep) {
    int e = rep * 256 + t;
    int row = e >> 6, col = e & 63;
    float wd = W[(128 + row) * 64 + col];
    float wm = qpart ? (W[row * 64 + col] + wd)
                     : (W[(64 + row) * 64 + col] - wd);
    wcomb[row][col] = wm;
    xin[row][col] = src[(r0 + row) * 64 + col];
  }
  __syncthreads();
  const int r = t >> 2;
  const int h0 = (t & 3) << 4;
  float acc[16];
#pragma unroll
  for (int k = 0; k < 16; ++k) acc[k] = 0.f;
#pragma unroll 8
  for (int d = 0; d < 64; ++d) {
    float xv = xin[r][d];
#pragma unroll
    for (int c = 0; c < 4; ++c) {
      float4 w4 = *(const float4*)&wcomb[d][h0 + (c << 2)];
      acc[c * 4 + 0] = fmaf(xv, w4.x, acc[c * 4 + 0]);
      acc[c * 4 + 1] = fmaf(xv, w4.y, acc[c * 4 + 1]);
      acc[c * 4 + 2] = fmaf(xv, w4.z, acc[c * 4 + 2]);
      acc[c * 4 + 3] = fmaf(xv, w4.w, acc[c * 4 + 3]);
    }
  }
  int grow = r0 + r;
  if (qpart) {
    unsigned pr[8];
#pragma unroll
    for (int i = 0; i < 8; ++i) pr[i] = pkrtz_u32(acc[2 * i], acc[2 * i + 1]);
    uint4* dst = (uint4*)&hq2[grow * 32 + (t & 3) * 8];
    dst[0] = make_uint4(pr[0], pr[1], pr[2], pr[3]);
    dst[1] = make_uint4(pr[4], pr[5], pr[6], pr[7]);
  } else {
    int bidx = grow >> 10;
    int j = grow & 1023;
    float val[16];
    float part = 0.f;
#pragma unroll
    for (int k = 0; k < 16; ++k) {
      val[k] = acc[k] + bias[h0 + k];
      part += a[h0 + k] * val[k];
    }
    part += __shfl_xor(part, 1);
    part += __shfl_xor(part, 2);
    if ((t & 3) == 0) Dj[bidx * 1024 + j] = 0.075f * part;
    unsigned pr[8];
#pragma unroll
    for (int i = 0; i < 8; ++i) pr[i] = pkrtz_u32(val[2 * i], val[2 * i + 1]);
    const int h4a = (t & 3) * 2;
    khT4[(bidx * 8 + h4a) * 1024 + j]     = make_uint4(pr[0], pr[1], pr[2], pr[3]);
    khT4[(bidx * 8 + h4a + 1) * 1024 + j] = make_uint4(pr[4], pr[5], pr[6], pr[7]);
  }
}

// ---------------- Kernel B: 4 rows x 1024 j; ping-pong scores; MFMA PV --------
__global__ __launch_bounds__(256) void attn12_kernel(
    const uint4* __restrict__ vfrag,
    const unsigned* __restrict__ hq2, const uint4* __restrict__ khT4,
    const float* __restrict__ Dj, const unsigned* __restrict__ abd2,
    float* __restrict__ out) {
  __shared__ __align__(16) unsigned p2u[4 * 520];  // p f16 pairs, padded rows
  __shared__ __align__(16) float ob[16 * 64];
  __shared__ __align__(16) unsigned q2lds[128];
  __shared__ __align__(16) unsigned ab2lds[32];
  __shared__ float redm[4][4];  // [r][w] per-wave max
  __shared__ float redl[4][4];  // [r][w] per-wave sum (own-max scale)

  const int t = threadIdx.x;
  const int lane = t & 63;
  const int w = t >> 6;
  const int b = blockIdx.y;
  const int rowbase = blockIdx.x * 4;
  const int growbase = b * 1024 + rowbase;

  const uint4* kh_b = khT4 + (size_t)b * 8 * 1024;
  const uint4* vf_b = vfrag + (size_t)b * 32 * 4 * 64;

  if (t < 128) q2lds[t] = hq2[growbase * 32 + t];
  if (t >= 128 && t < 160) ab2lds[t - 128] = abd2[t - 128];
  __syncthreads();

  const int jloc = w * 256 + lane * 4;
  float4 d4 = *(const float4*)(Dj + b * 1024 + jloc);

  float s[4][4];
#pragma unroll
  for (int r = 0; r < 4; ++r)
#pragma unroll
    for (int c = 0; c < 4; ++c) s[r][c] = 0.f;

  auto SCORE = [&](const uint4 (&K)[4], int it) {
    uint4 abq = *(const uint4*)&ab2lds[it * 4];
    unsigned abu[4] = {abq.x, abq.y, abq.z, abq.w};
    unsigned ku[4][4] = {{K[0].x, K[0].y, K[0].z, K[0].w},
                         {K[1].x, K[1].y, K[1].z, K[1].w},
                         {K[2].x, K[2].y, K[2].z, K[2].w},
                         {K[3].x, K[3].y, K[3].z, K[3].w}};
#pragma unroll
    for (int r = 0; r < 4; ++r) {
      uint4 qq = *(const uint4*)&q2lds[r * 32 + it * 4];
      unsigned qu[4] = {qq.x, qq.y, qq.z, qq.w};
#pragma unroll
      for (int u = 0; u < 4; ++u) {
        h2v qh = u2h(qu[u]);
        h2v a2 = u2h(abu[u]);
#pragma unroll
        for (int c = 0; c < 4; ++c) {
          h2v x = habs2(qh + u2h(ku[c][u]));
          s[r][c] = __builtin_amdgcn_fdot2(a2, x, s[r][c], false);
        }
      }
    }
  };

  // ---- scores: ping-pong double buffer (no loop-carried copies) ----
  uint4 kA[4], kB[4];
#pragma unroll
  for (int c = 0; c < 4; ++c) kA[c] = kh_b[jloc + c];
#pragma unroll
  for (int c = 0; c < 4; ++c) kB[c] = kh_b[1024 + jloc + c];
#pragma unroll 1
  for (int it2 = 0; it2 < 4; ++it2) {
    const int itA = 2 * it2, itB = 2 * it2 + 1;
    const int nA = (itA + 2 < 8) ? itA + 2 : itA;  // last: harmless reload
    const int nB = (itB + 2 < 8) ? itB + 2 : itB;
    SCORE(kA, itA);
#pragma unroll
    for (int c = 0; c < 4; ++c) kA[c] = kh_b[nA * 1024 + jloc + c];
    SCORE(kB, itB);
#pragma unroll
    for (int c = 0; c < 4; ++c) kB[c] = kh_b[nB * 1024 + jloc + c];
  }
#pragma unroll
  for (int r = 0; r < 4; ++r) {
    s[r][0] += d4.x; s[r][1] += d4.y; s[r][2] += d4.z; s[r][3] += d4.w;
  }

  // ---- per-wave softmax (own max; cross-wave combine at output) ----
  float mw[4];
#pragma unroll
  for (int r = 0; r < 4; ++r) {
    float m = fmaxf(fmaxf(s[r][0], s[r][1]), fmaxf(s[r][2], s[r][3]));
#pragma unroll
    for (int off = 32; off >= 1; off >>= 1) m = fmaxf(m, __shfl_xor(m, off));
    mw[r] = m;
    if (lane == 0) redm[r][w] = m;
  }
#pragma unroll
  for (int r = 0; r < 4; ++r) {
    float p0 = __builtin_amdgcn_exp2f((s[r][0] - mw[r]) * LOG2E);
    float p1 = __builtin_amdgcn_exp2f((s[r][1] - mw[r]) * LOG2E);
    float p2 = __builtin_amdgcn_exp2f((s[r][2] - mw[r]) * LOG2E);
    float p3 = __builtin_amdgcn_exp2f((s[r][3] - mw[r]) * LOG2E);
    *(uint2*)&p2u[r * 520 + (jloc >> 1)] =
        make_uint2(pkrtz_u32(p0, p1), pkrtz_u32(p2, p3));
    float ps = (p0 + p1) + (p2 + p3);
#pragma unroll
    for (int off = 32; off >= 1; off >>= 1) ps += __shfl_xor(ps, off);
    if (lane == 0) redl[r][w] = ps;
  }
  __syncthreads();  // p2u, redm, redl visible

  // ---- PV via MFMA over this wave's 256-j chunk ----
  f32x4 acc[4];
#pragma unroll
  for (int nt = 0; nt < 4; ++nt) acc[nt] = (f32x4){0.f, 0.f, 0.f, 0.f};
  const int arow = (lane & 3) * 520;
  const int kgr = (lane >> 4) * 8;
#pragma unroll 2
  for (int ks = 0; ks < 8; ++ks) {
    const int j0 = w * 256 + ks * 32;
    uint4 au = *(const uint4*)&p2u[arow + ((j0 + kgr) >> 1)];
    f16x8 af; __builtin_memcpy(&af, &au, 16);
    const int gks = j0 >> 5;
#pragma unroll
    for (int nt = 0; nt < 4; ++nt) {
      uint4 bu = vf_b[(gks * 4 + nt) * 64 + lane];
      f16x8 bf; __builtin_memcpy(&bf, &bu, 16);
      acc[nt] = __builtin_amdgcn_mfma_f32_16x16x32_f16(af, bf, acc[nt], 0, 0, 0);
    }
  }

  // rescale this wave's O by exp(m_w - M) and store partials
  float4 rmv[1];
  float eww[4];
#pragma unroll
  for (int r = 0; r < 4; ++r) {
    float4 rm = *(const float4*)&redm[r][0];
    float M = fmaxf(fmaxf(rm.x, rm.y), fmaxf(rm.z, rm.w));
    float mwv = (w == 0) ? rm.x : (w == 1) ? rm.y : (w == 2) ? rm.z : rm.w;
    eww[r] = __builtin_amdgcn_exp2f((mwv - M) * LOG2E);
  }
  if (lane < 16) {
#pragma unroll
    for (int nt = 0; nt < 4; ++nt)
#pragma unroll
      for (int rg = 0; rg < 4; ++rg)
        ob[(w * 4 + rg) * 64 + nt * 16 + lane] = acc[nt][rg] * eww[rg];
  }
  __syncthreads();
  {
    int r = t >> 6, d = t & 63;
    float ax = 0.f;
#pragma unroll
    for (int wv = 0; wv < 4; ++wv) ax += ob[(wv * 4 + r) * 64 + d];
    float4 rm = *(const float4*)&redm[r][0];
    float M = fmaxf(fmaxf(rm.x, rm.y), fmaxf(rm.z, rm.w));
    float4 rl = *(const float4*)&redl[r][0];
    float lt = rl.x * __builtin_amdgcn_exp2f((rm.x - M) * LOG2E) +
               rl.y * __builtin_amdgcn_exp2f((rm.y - M) * LOG2E) +
               rl.z * __builtin_amdgcn_exp2f((rm.z - M) * LOG2E) +
               rl.w * __builtin_amdgcn_exp2f((rm.w - M) * LOG2E);
    out[(growbase + r) * 64 + d] = ax / lt;
  }
}

extern "C" void kernel_launch(void* const* d_in, const int* in_sizes, int n_in,
                              void* d_out, int out_size, void* d_ws, size_t ws_size,
                              hipStream_t stream) {
  const float* qs = (const float*)d_in[0];
  const float* ks = (const float*)d_in[1];
  const float* vs = (const float*)d_in[2];
  const float* W  = (const float*)d_in[3];
  const float* bi = (const float*)d_in[4];
  const float* a  = (const float*)d_in[5];
  float* out = (float*)d_out;
  unsigned* hq2   = (unsigned*)d_ws;                    // 512KB
  uint4*    khT4  = (uint4*)((char*)d_ws + 524288);     // 512KB
  float*    Dj    = (float*)((char*)d_ws + 1048576);    // 16KB
  unsigned* abd2  = (unsigned*)((char*)d_ws + 1064960); // 128B
  uint4*    vfrag = (uint4*)((char*)d_ws + 1065216);    // 512KB
  prep_kernel<<<256, 256, 0, stream>>>(qs, ks, vs, W, bi, a, hq2, khT4, Dj,
                                       abd2, vfrag);
  attn12_kernel<<<dim3(256, 4), 256, 0, stream>>>(vfrag, hq2, khT4, Dj, abd2, out);
}

// Round 13
// 36.640 us; speedup vs baseline: 1.5634x; 1.5634x over previous
//
#include <hip/hip_runtime.h>
#include <math.h>

#define LOG2E 1.4426950408889634f
typedef __attribute__((ext_vector_type(2))) _Float16 h2v;
typedef __attribute__((ext_vector_type(8))) _Float16 f16x8;
typedef __attribute__((ext_vector_type(4))) float f32x4;

static __device__ __forceinline__ unsigned pkrtz_u32(float lo, float hi) {
  auto p = __builtin_amdgcn_cvt_pkrtz(lo, hi);
  unsigned u; __builtin_memcpy(&u, &p, 4); return u;
}
static __device__ __forceinline__ h2v habs2(h2v x) {
  unsigned u; __builtin_memcpy(&u, &x, 4);
  u &= 0x7FFF7FFFu;
  h2v r; __builtin_memcpy(&r, &u, 4); return r;
}
static __device__ __forceinline__ h2v u2h(unsigned u) {
  h2v r; __builtin_memcpy(&r, &u, 4); return r;
}

// s[i,j] = Ci + Dj + sum_h ab_h*|hq_ih + hkb_jh|, ab=0.05a, Dj=0.075(a.hkb_j)
// Ci per-row -> cancels in softmax -> dropped.
// khT4: [b][h4][j] uint4 = f16 pairs of h=8*h4..8*h4+7 (bias folded).
// hq2: [row][h2] u32 f16 pairs. abd2: [h2] u32 pairs of 0.05a.
// vfrag: [b][kstep][ntile][lane] uint4 — V in MFMA B-frag order.

// ---------------- Kernel A: prep (blocks 0-127) + vpack (blocks 128-255) ------
__global__ __launch_bounds__(256) void prep_kernel(
    const float* __restrict__ qs, const float* __restrict__ ks,
    const float* __restrict__ vs,
    const float* __restrict__ W, const float* __restrict__ bias,
    const float* __restrict__ a,
    unsigned* __restrict__ hq2, uint4* __restrict__ khT4,
    float* __restrict__ Dj, unsigned* __restrict__ abd2,
    uint4* __restrict__ vfrag) {
  __shared__ __align__(16) float wcomb[64][68];
  __shared__ __align__(16) float xin[64][68];
  const int blk = blockIdx.x;
  const int t = threadIdx.x;

  if (blk >= 128) {  // ---- vpack: V -> MFMA B-fragment f16 layout ----
    const int unit = blk - 128;             // b = unit>>5, kstep = unit&31
    const int b = unit >> 5, kstep = unit & 31;
    const int lane = t & 63, ntile = t >> 6;
    const int j0 = kstep * 32 + (lane >> 4) * 8;
    const int d = ntile * 16 + (lane & 15);
    const float* vb = vs + b * 1024 * 64;
    unsigned pr[4];
#pragma unroll
    for (int i = 0; i < 4; ++i)
      pr[i] = pkrtz_u32(vb[(j0 + 2 * i) * 64 + d], vb[(j0 + 2 * i + 1) * 64 + d]);
    vfrag[((b * 32 + kstep) * 4 + ntile) * 64 + lane] =
        make_uint4(pr[0], pr[1], pr[2], pr[3]);
    return;
  }

  const bool qpart = blk < 64;
  const int r0 = (qpart ? blk : blk - 64) * 64;
  const float* src = qpart ? qs : ks;
  if (blk == 0 && t < 32)
    abd2[t] = pkrtz_u32(0.05f * a[2 * t], 0.05f * a[2 * t + 1]);
  for (int rep = 0; rep < 16; ++rep) {
    int e = rep * 256 + t;
    int row = e >> 6, col = e & 63;
    float wd = W[(128 + row) * 64 + col];
    float wm = qpart ? (W[row * 64 + col] + wd)
                     : (W[(64 + row) * 64 + col] - wd);
    wcomb[row][col] = wm;
    xin[row][col] = src[(r0 + row) * 64 + col];
  }
  __syncthreads();
  const int r = t >> 2;
  const int h0 = (t & 3) << 4;
  float acc[16];
#pragma unroll
  for (int k = 0; k < 16; ++k) acc[k] = 0.f;
#pragma unroll 8
  for (int d = 0; d < 64; ++d) {
    float xv = xin[r][d];
#pragma unroll
    for (int c = 0; c < 4; ++c) {
      float4 w4 = *(const float4*)&wcomb[d][h0 + (c << 2)];
      acc[c * 4 + 0] = fmaf(xv, w4.x, acc[c * 4 + 0]);
      acc[c * 4 + 1] = fmaf(xv, w4.y, acc[c * 4 + 1]);
      acc[c * 4 + 2] = fmaf(xv, w4.z, acc[c * 4 + 2]);
      acc[c * 4 + 3] = fmaf(xv, w4.w, acc[c * 4 + 3]);
    }
  }
  int grow = r0 + r;
  if (qpart) {
    unsigned pr[8];
#pragma unroll
    for (int i = 0; i < 8; ++i) pr[i] = pkrtz_u32(acc[2 * i], acc[2 * i + 1]);
    uint4* dst = (uint4*)&hq2[grow * 32 + (t & 3) * 8];
    dst[0] = make_uint4(pr[0], pr[1], pr[2], pr[3]);
    dst[1] = make_uint4(pr[4], pr[5], pr[6], pr[7]);
  } else {
    int bidx = grow >> 10;
    int j = grow & 1023;
    float val[16];
    float part = 0.f;
#pragma unroll
    for (int k = 0; k < 16; ++k) {
      val[k] = acc[k] + bias[h0 + k];
      part += a[h0 + k] * val[k];
    }
    part += __shfl_xor(part, 1);
    part += __shfl_xor(part, 2);
    if ((t & 3) == 0) Dj[bidx * 1024 + j] = 0.075f * part;
    unsigned pr[8];
#pragma unroll
    for (int i = 0; i < 8; ++i) pr[i] = pkrtz_u32(val[2 * i], val[2 * i + 1]);
    const int h4a = (t & 3) * 2;
    khT4[(bidx * 8 + h4a) * 1024 + j]     = make_uint4(pr[0], pr[1], pr[2], pr[3]);
    khT4[(bidx * 8 + h4a + 1) * 1024 + j] = make_uint4(pr[4], pr[5], pr[6], pr[7]);
  }
}

// ---------------- Kernel B: 4 rows x 1024 j; f16 dot2 scores; MFMA PV --------
// (r11's proven attn11 body, verbatim)
__global__ __launch_bounds__(256) void attn13_kernel(
    const uint4* __restrict__ vfrag,
    const unsigned* __restrict__ hq2, const uint4* __restrict__ khT4,
    const float* __restrict__ Dj, const unsigned* __restrict__ abd2,
    float* __restrict__ out) {
  __shared__ __align__(16) unsigned p2u[4 * 520];   // p f16 pairs, row pad
  __shared__ __align__(16) float ob[16 * 64];
  __shared__ __align__(16) unsigned q2lds[4 * 32];
  __shared__ __align__(16) unsigned ab2lds[32];
  __shared__ float redm[4][4];
  __shared__ float redl[4][4];

  const int t = threadIdx.x;
  const int lane = t & 63;
  const int w = t >> 6;
  const int b = blockIdx.y;
  const int rowbase = blockIdx.x * 4;
  const int growbase = b * 1024 + rowbase;

  const uint4* kh_b = khT4 + (size_t)b * 8 * 1024;
  const uint4* vf_b = vfrag + (size_t)b * 32 * 4 * 64;

  if (t < 128) q2lds[t] = hq2[growbase * 32 + t];
  if (t >= 128 && t < 160) ab2lds[t - 128] = abd2[t - 128];
  __syncthreads();

  const int jloc = w * 256 + lane * 4;  // lane owns j = jloc..jloc+3
  float4 d4 = *(const float4*)(Dj + b * 1024 + jloc);

  float s[4][4];
#pragma unroll
  for (int r = 0; r < 4; ++r)
#pragma unroll
    for (int c = 0; c < 4; ++c) s[r][c] = 0.f;

  // ---- scores: per h4-group (8 h), k double-buffered in regs ----
  uint4 kc0 = kh_b[jloc], kc1 = kh_b[jloc + 1], kc2 = kh_b[jloc + 2],
        kc3 = kh_b[jloc + 3];
#pragma unroll 1
  for (int it = 0; it < 8; ++it) {
    const int nx = (it < 7) ? it + 1 : it;  // last iter: harmless reload
    uint4 kn0 = kh_b[nx * 1024 + jloc];
    uint4 kn1 = kh_b[nx * 1024 + jloc + 1];
    uint4 kn2 = kh_b[nx * 1024 + jloc + 2];
    uint4 kn3 = kh_b[nx * 1024 + jloc + 3];
    uint4 abq = *(const uint4*)&ab2lds[it * 4];
    const unsigned abu[4] = {abq.x, abq.y, abq.z, abq.w};
    const unsigned kcu[4][4] = {{kc0.x, kc0.y, kc0.z, kc0.w},
                                {kc1.x, kc1.y, kc1.z, kc1.w},
                                {kc2.x, kc2.y, kc2.z, kc2.w},
                                {kc3.x, kc3.y, kc3.z, kc3.w}};
#pragma unroll
    for (int r = 0; r < 4; ++r) {
      uint4 qq = *(const uint4*)&q2lds[r * 32 + it * 4];
      const unsigned qu[4] = {qq.x, qq.y, qq.z, qq.w};
#pragma unroll
      for (int u = 0; u < 4; ++u) {
        h2v qh = u2h(qu[u]);
        h2v a2 = u2h(abu[u]);
#pragma unroll
        for (int c = 0; c < 4; ++c) {
          h2v x = habs2(qh + u2h(kcu[c][u]));
          s[r][c] = __builtin_amdgcn_fdot2(a2, x, s[r][c], false);
        }
      }
    }
    kc0 = kn0; kc1 = kn1; kc2 = kn2; kc3 = kn3;
  }
#pragma unroll
  for (int r = 0; r < 4; ++r) {
    s[r][0] += d4.x; s[r][1] += d4.y; s[r][2] += d4.z; s[r][3] += d4.w;
  }

  // ---- exact softmax over 1024 j ----
#pragma unroll
  for (int r = 0; r < 4; ++r) {
    float m = fmaxf(fmaxf(s[r][0], s[r][1]), fmaxf(s[r][2], s[r][3]));
#pragma unroll
    for (int off = 32; off >= 1; off >>= 1) m = fmaxf(m, __shfl_xor(m, off));
    if (lane == 0) redm[r][w] = m;
  }
  __syncthreads();
  float mx[4];
#pragma unroll
  for (int r = 0; r < 4; ++r) {
    float4 rm = *(const float4*)&redm[r][0];
    mx[r] = fmaxf(fmaxf(rm.x, rm.y), fmaxf(rm.z, rm.w));
  }
#pragma unroll
  for (int r = 0; r < 4; ++r) {
    float p0 = __builtin_amdgcn_exp2f((s[r][0] - mx[r]) * LOG2E);
    float p1 = __builtin_amdgcn_exp2f((s[r][1] - mx[r]) * LOG2E);
    float p2 = __builtin_amdgcn_exp2f((s[r][2] - mx[r]) * LOG2E);
    float p3 = __builtin_amdgcn_exp2f((s[r][3] - mx[r]) * LOG2E);
    *(uint2*)&p2u[r * 520 + (jloc >> 1)] =
        make_uint2(pkrtz_u32(p0, p1), pkrtz_u32(p2, p3));
    float ps = (p0 + p1) + (p2 + p3);
#pragma unroll
    for (int off = 32; off >= 1; off >>= 1) ps += __shfl_xor(ps, off);
    if (lane == 0) redl[r][w] = ps;
  }
  __syncthreads();

  // ---- PV via MFMA: wave w handles K-chunk j = w*256..w*256+255 ----
  f32x4 acc[4];
#pragma unroll
  for (int nt = 0; nt < 4; ++nt) acc[nt] = (f32x4){0.f, 0.f, 0.f, 0.f};
  const int arow = (lane & 3) * 520;
  const int kgr = (lane >> 4) * 8;
#pragma unroll 2
  for (int ks = 0; ks < 8; ++ks) {
    const int j0 = w * 256 + ks * 32;
    uint4 au = *(const uint4*)&p2u[arow + ((j0 + kgr) >> 1)];
    f16x8 af; __builtin_memcpy(&af, &au, 16);
    const int gks = j0 >> 5;
#pragma unroll
    for (int nt = 0; nt < 4; ++nt) {
      uint4 bu = vf_b[(gks * 4 + nt) * 64 + lane];
      f16x8 bf; __builtin_memcpy(&bf, &bu, 16);
      acc[nt] = __builtin_amdgcn_mfma_f32_16x16x32_f16(af, bf, acc[nt], 0, 0, 0);
    }
  }

  // C rows 0-3 live in lanes 0-15, reg = row
  if (lane < 16) {
#pragma unroll
    for (int nt = 0; nt < 4; ++nt)
#pragma unroll
      for (int rg = 0; rg < 4; ++rg)
        ob[(w * 4 + rg) * 64 + nt * 16 + lane] = acc[nt][rg];
  }
  __syncthreads();
  {
    int r = t >> 6, d = t & 63;  // r == w (wave-uniform)
    float ax = 0.f;
#pragma unroll
    for (int wv = 0; wv < 4; ++wv) ax += ob[(wv * 4 + r) * 64 + d];
    float4 rl = *(const float4*)&redl[r][0];
    float inv = 1.f / ((rl.x + rl.y) + (rl.z + rl.w));
    out[(growbase + r) * 64 + d] = ax * inv;
  }
}

extern "C" void kernel_launch(void* const* d_in, const int* in_sizes, int n_in,
                              void* d_out, int out_size, void* d_ws, size_t ws_size,
                              hipStream_t stream) {
  const float* qs = (const float*)d_in[0];
  const float* ks = (const float*)d_in[1];
  const float* vs = (const float*)d_in[2];
  const float* W  = (const float*)d_in[3];
  const float* bi = (const float*)d_in[4];
  const float* a  = (const float*)d_in[5];
  float* out = (float*)d_out;
  unsigned* hq2   = (unsigned*)d_ws;                    // 512KB
  uint4*    khT4  = (uint4*)((char*)d_ws + 524288);     // 512KB
  float*    Dj    = (float*)((char*)d_ws + 1048576);    // 16KB
  unsigned* abd2  = (unsigned*)((char*)d_ws + 1064960); // 128B
  uint4*    vfrag = (uint4*)((char*)d_ws + 1065216);    // 512KB
  prep_kernel<<<256, 256, 0, stream>>>(qs, ks, vs, W, bi, a, hq2, khT4, Dj,
                                       abd2, vfrag);
  attn13_kernel<<<dim3(256, 4), 256, 0, stream>>>(vfrag, hq2, khT4, Dj, abd2, out);
}

// Round 14
// 36.299 us; speedup vs baseline: 1.5781x; 1.0094x over previous
//
#include <hip/hip_runtime.h>
#include <math.h>

#define LOG2E 1.4426950408889634f
typedef __attribute__((ext_vector_type(2))) _Float16 h2v;
typedef __attribute__((ext_vector_type(8))) _Float16 f16x8;
typedef __attribute__((ext_vector_type(4))) float f32x4;

static __device__ __forceinline__ unsigned pkrtz_u32(float lo, float hi) {
  auto p = __builtin_amdgcn_cvt_pkrtz(lo, hi);
  unsigned u; __builtin_memcpy(&u, &p, 4); return u;
}
static __device__ __forceinline__ h2v habs2(h2v x) {
  unsigned u; __builtin_memcpy(&u, &x, 4);
  u &= 0x7FFF7FFFu;
  h2v r; __builtin_memcpy(&r, &u, 4); return r;
}
static __device__ __forceinline__ h2v u2h(unsigned u) {
  h2v r; __builtin_memcpy(&r, &u, 4); return r;
}

// s[i,j] = Ci + Dj + sum_h ab_h*|hq_ih + hkb_jh|, ab=0.05a, Dj=0.075(a.hkb_j)
// Ci per-row -> cancels in softmax -> dropped.
// khT4: [b][h4][j] uint4 = f16 pairs of h=8*h4..8*h4+7 (bias folded).
// hq2: [row][h2] u32 f16 pairs. abd2: [h2] u32 pairs of 0.05a.
// vfrag: [b][kstep][ntile][lane] uint4 — V in MFMA B-frag order.

// ---------------- Kernel A: prep (blocks 0-127) + vpack (blocks 128-255) ------
__global__ __launch_bounds__(256) void prep_kernel(
    const float* __restrict__ qs, const float* __restrict__ ks,
    const float* __restrict__ vs,
    const float* __restrict__ W, const float* __restrict__ bias,
    const float* __restrict__ a,
    unsigned* __restrict__ hq2, uint4* __restrict__ khT4,
    float* __restrict__ Dj, unsigned* __restrict__ abd2,
    uint4* __restrict__ vfrag) {
  __shared__ __align__(16) float wcomb[64][68];
  __shared__ __align__(16) float xin[64][68];
  const int blk = blockIdx.x;
  const int t = threadIdx.x;

  if (blk >= 128) {  // ---- vpack: V -> MFMA B-fragment f16 layout ----
    const int unit = blk - 128;             // b = unit>>5, kstep = unit&31
    const int b = unit >> 5, kstep = unit & 31;
    const int lane = t & 63, ntile = t >> 6;
    const int j0 = kstep * 32 + (lane >> 4) * 8;
    const int d = ntile * 16 + (lane & 15);
    const float* vb = vs + b * 1024 * 64;
    unsigned pr[4];
#pragma unroll
    for (int i = 0; i < 4; ++i)
      pr[i] = pkrtz_u32(vb[(j0 + 2 * i) * 64 + d], vb[(j0 + 2 * i + 1) * 64 + d]);
    vfrag[((b * 32 + kstep) * 4 + ntile) * 64 + lane] =
        make_uint4(pr[0], pr[1], pr[2], pr[3]);
    return;
  }

  const bool qpart = blk < 64;
  const int r0 = (qpart ? blk : blk - 64) * 64;
  const float* src = qpart ? qs : ks;
  if (blk == 0 && t < 32)
    abd2[t] = pkrtz_u32(0.05f * a[2 * t], 0.05f * a[2 * t + 1]);
  for (int rep = 0; rep < 16; ++rep) {
    int e = rep * 256 + t;
    int row = e >> 6, col = e & 63;
    float wd = W[(128 + row) * 64 + col];
    float wm = qpart ? (W[row * 64 + col] + wd)
                     : (W[(64 + row) * 64 + col] - wd);
    wcomb[row][col] = wm;
    xin[row][col] = src[(r0 + row) * 64 + col];
  }
  __syncthreads();
  const int r = t >> 2;
  const int h0 = (t & 3) << 4;
  float acc[16];
#pragma unroll
  for (int k = 0; k < 16; ++k) acc[k] = 0.f;
#pragma unroll 8
  for (int d = 0; d < 64; ++d) {
    float xv = xin[r][d];
#pragma unroll
    for (int c = 0; c < 4; ++c) {
      float4 w4 = *(const float4*)&wcomb[d][h0 + (c << 2)];
      acc[c * 4 + 0] = fmaf(xv, w4.x, acc[c * 4 + 0]);
      acc[c * 4 + 1] = fmaf(xv, w4.y, acc[c * 4 + 1]);
      acc[c * 4 + 2] = fmaf(xv, w4.z, acc[c * 4 + 2]);
      acc[c * 4 + 3] = fmaf(xv, w4.w, acc[c * 4 + 3]);
    }
  }
  int grow = r0 + r;
  if (qpart) {
    unsigned pr[8];
#pragma unroll
    for (int i = 0; i < 8; ++i) pr[i] = pkrtz_u32(acc[2 * i], acc[2 * i + 1]);
    uint4* dst = (uint4*)&hq2[grow * 32 + (t & 3) * 8];
    dst[0] = make_uint4(pr[0], pr[1], pr[2], pr[3]);
    dst[1] = make_uint4(pr[4], pr[5], pr[6], pr[7]);
  } else {
    int bidx = grow >> 10;
    int j = grow & 1023;
    float val[16];
    float part = 0.f;
#pragma unroll
    for (int k = 0; k < 16; ++k) {
      val[k] = acc[k] + bias[h0 + k];
      part += a[h0 + k] * val[k];
    }
    part += __shfl_xor(part, 1);
    part += __shfl_xor(part, 2);
    if ((t & 3) == 0) Dj[bidx * 1024 + j] = 0.075f * part;
    unsigned pr[8];
#pragma unroll
    for (int i = 0; i < 8; ++i) pr[i] = pkrtz_u32(val[2 * i], val[2 * i + 1]);
    const int h4a = (t & 3) * 2;
    khT4[(bidx * 8 + h4a) * 1024 + j]     = make_uint4(pr[0], pr[1], pr[2], pr[3]);
    khT4[(bidx * 8 + h4a + 1) * 1024 + j] = make_uint4(pr[4], pr[5], pr[6], pr[7]);
  }
}

// ---------------- Kernel B: 8 rows x 1024 j; 8 waves; f16 dot2; MFMA PV ------
__global__ __launch_bounds__(512) void attn14_kernel(
    const uint4* __restrict__ vfrag,
    const unsigned* __restrict__ hq2, const uint4* __restrict__ khT4,
    const float* __restrict__ Dj, const unsigned* __restrict__ abd2,
    float* __restrict__ out) {
  __shared__ __align__(16) unsigned p2u[8 * 520];   // p f16 pairs, row pad
  __shared__ __align__(16) float ob[64 * 64];       // [8w][8r][64d] 16KB
  __shared__ __align__(16) unsigned q2lds[8 * 32];
  __shared__ __align__(16) unsigned ab2lds[32];
  __shared__ float redm[8][8];
  __shared__ float redl[8][8];

  const int t = threadIdx.x;
  const int lane = t & 63;
  const int w = t >> 6;          // 0..7
  const int b = blockIdx.y;
  const int rowbase = blockIdx.x * 8;
  const int growbase = b * 1024 + rowbase;

  const uint4* kh_b = khT4 + (size_t)b * 8 * 1024;
  const uint4* vf_b = vfrag + (size_t)b * 32 * 4 * 64;

  if (t < 256) q2lds[t] = hq2[growbase * 32 + t];
  if (t >= 256 && t < 288) ab2lds[t - 256] = abd2[t - 256];
  __syncthreads();

  const int jloc = w * 128 + lane * 2;  // lane owns j = jloc, jloc+1
  float2 d2 = *(const float2*)(Dj + b * 1024 + jloc);

  float s[8][2];
#pragma unroll
  for (int r = 0; r < 8; ++r) { s[r][0] = 0.f; s[r][1] = 0.f; }

  // ---- scores: per h4-group (8 h), k double-buffered in regs ----
  uint4 kc0 = kh_b[jloc], kc1 = kh_b[jloc + 1];
#pragma unroll 1
  for (int it = 0; it < 8; ++it) {
    const int nx = (it < 7) ? it + 1 : it;  // last iter: harmless reload
    uint4 kn0 = kh_b[nx * 1024 + jloc];
    uint4 kn1 = kh_b[nx * 1024 + jloc + 1];
    uint4 abq = *(const uint4*)&ab2lds[it * 4];
    const unsigned abu[4] = {abq.x, abq.y, abq.z, abq.w};
    const unsigned kcu[2][4] = {{kc0.x, kc0.y, kc0.z, kc0.w},
                                {kc1.x, kc1.y, kc1.z, kc1.w}};
#pragma unroll
    for (int r = 0; r < 8; ++r) {
      uint4 qq = *(const uint4*)&q2lds[r * 32 + it * 4];
      const unsigned qu[4] = {qq.x, qq.y, qq.z, qq.w};
#pragma unroll
      for (int u = 0; u < 4; ++u) {
        h2v qh = u2h(qu[u]);
        h2v a2 = u2h(abu[u]);
        h2v x0 = habs2(qh + u2h(kcu[0][u]));
        s[r][0] = __builtin_amdgcn_fdot2(a2, x0, s[r][0], false);
        h2v x1 = habs2(qh + u2h(kcu[1][u]));
        s[r][1] = __builtin_amdgcn_fdot2(a2, x1, s[r][1], false);
      }
    }
    kc0 = kn0; kc1 = kn1;
  }
#pragma unroll
  for (int r = 0; r < 8; ++r) { s[r][0] += d2.x; s[r][1] += d2.y; }

  // ---- exact softmax over 1024 j (cross-lane + cross-wave) ----
#pragma unroll
  for (int r = 0; r < 8; ++r) {
    float m = fmaxf(s[r][0], s[r][1]);
#pragma unroll
    for (int off = 32; off >= 1; off >>= 1) m = fmaxf(m, __shfl_xor(m, off));
    if (lane == 0) redm[r][w] = m;
  }
  __syncthreads();
  float mx[8];
#pragma unroll
  for (int r = 0; r < 8; ++r) {
    float4 a0 = *(const float4*)&redm[r][0];
    float4 a1 = *(const float4*)&redm[r][4];
    mx[r] = fmaxf(fmaxf(fmaxf(a0.x, a0.y), fmaxf(a0.z, a0.w)),
                  fmaxf(fmaxf(a1.x, a1.y), fmaxf(a1.z, a1.w)));
  }
#pragma unroll
  for (int r = 0; r < 8; ++r) {
    float p0 = __builtin_amdgcn_exp2f((s[r][0] - mx[r]) * LOG2E);
    float p1 = __builtin_amdgcn_exp2f((s[r][1] - mx[r]) * LOG2E);
    p2u[r * 520 + (jloc >> 1)] = pkrtz_u32(p0, p1);
    float ps = p0 + p1;
#pragma unroll
    for (int off = 32; off >= 1; off >>= 1) ps += __shfl_xor(ps, off);
    if (lane == 0) redl[r][w] = ps;
  }
  __syncthreads();

  // ---- PV via MFMA: wave w handles K-chunk j = w*128..w*128+127 ----
  f32x4 acc[4];
#pragma unroll
  for (int nt = 0; nt < 4; ++nt) acc[nt] = (f32x4){0.f, 0.f, 0.f, 0.f};
  const int arow = (lane & 7) * 520;  // A rows 8-15 alias 0-7 (C rows 8-15 unused)
  const int kgr = (lane >> 4) * 8;
#pragma unroll 2
  for (int ks = 0; ks < 4; ++ks) {
    const int j0 = w * 128 + ks * 32;
    uint4 au = *(const uint4*)&p2u[arow + ((j0 + kgr) >> 1)];
    f16x8 af; __builtin_memcpy(&af, &au, 16);
    const int gks = j0 >> 5;
#pragma unroll
    for (int nt = 0; nt < 4; ++nt) {
      uint4 bu = vf_b[(gks * 4 + nt) * 64 + lane];
      f16x8 bf; __builtin_memcpy(&bf, &bu, 16);
      acc[nt] = __builtin_amdgcn_mfma_f32_16x16x32_f16(af, bf, acc[nt], 0, 0, 0);
    }
  }

  // C rows 0-7 live in lanes 0-31: row = (lane>>4)*4 + reg
  if (lane < 32) {
    const int rbase = (lane >> 4) * 4;
#pragma unroll
    for (int nt = 0; nt < 4; ++nt)
#pragma unroll
      for (int rg = 0; rg < 4; ++rg)
        ob[(w * 8 + rbase + rg) * 64 + nt * 16 + (lane & 15)] = acc[nt][rg];
  }
  __syncthreads();
  {
    int r = t >> 6, d = t & 63;  // 512 threads cover 8 rows x 64 d
    float ax = 0.f;
#pragma unroll
    for (int wv = 0; wv < 8; ++wv) ax += ob[(wv * 8 + r) * 64 + d];
    float4 l0 = *(const float4*)&redl[r][0];
    float4 l1 = *(const float4*)&redl[r][4];
    float lt = ((l0.x + l0.y) + (l0.z + l0.w)) + ((l1.x + l1.y) + (l1.z + l1.w));
    out[(growbase + r) * 64 + d] = ax / lt;
  }
}

extern "C" void kernel_launch(void* const* d_in, const int* in_sizes, int n_in,
                              void* d_out, int out_size, void* d_ws, size_t ws_size,
                              hipStream_t stream) {
  const float* qs = (const float*)d_in[0];
  const float* ks = (const float*)d_in[1];
  const float* vs = (const float*)d_in[2];
  const float* W  = (const float*)d_in[3];
  const float* bi = (const float*)d_in[4];
  const float* a  = (const float*)d_in[5];
  float* out = (float*)d_out;
  unsigned* hq2   = (unsigned*)d_ws;                    // 512KB
  uint4*    khT4  = (uint4*)((char*)d_ws + 524288);     // 512KB
  float*    Dj    = (float*)((char*)d_ws + 1048576);    // 16KB
  unsigned* abd2  = (unsigned*)((char*)d_ws + 1064960); // 128B
  uint4*    vfrag = (uint4*)((char*)d_ws + 1065216);    // 512KB
  prep_kernel<<<256, 256, 0, stream>>>(qs, ks, vs, W, bi, a, hq2, khT4, Dj,
                                       abd2, vfrag);
  attn14_kernel<<<dim3(128, 4), 512, 0, stream>>>(vfrag, hq2, khT4, Dj, abd2, out);
}

// Round 15
// 34.055 us; speedup vs baseline: 1.6821x; 1.0659x over previous
//
#include <hip/hip_runtime.h>
#include <math.h>

#define LOG2E 1.4426950408889634f
typedef __attribute__((ext_vector_type(2))) _Float16 h2v;
typedef __attribute__((ext_vector_type(8))) _Float16 f16x8;
typedef __attribute__((ext_vector_type(4))) float f32x4;

static __device__ __forceinline__ unsigned pkrtz_u32(float lo, float hi) {
  auto p = __builtin_amdgcn_cvt_pkrtz(lo, hi);
  unsigned u; __builtin_memcpy(&u, &p, 4); return u;
}
static __device__ __forceinline__ h2v habs2(h2v x) {
  unsigned u; __builtin_memcpy(&u, &x, 4);
  u &= 0x7FFF7FFFu;
  h2v r; __builtin_memcpy(&r, &u, 4); return r;
}
static __device__ __forceinline__ h2v u2h(unsigned u) {
  h2v r; __builtin_memcpy(&r, &u, 4); return r;
}
static __device__ __forceinline__ unsigned pkmax_u(unsigned a, unsigned b) {
  h2v r = __builtin_elementwise_max(u2h(a), u2h(b));
  unsigned u; __builtin_memcpy(&u, &r, 4); return u;
}
static __device__ __forceinline__ float h2f(unsigned u, int idx) {
  h2v v = u2h(u);
  return (float)v[idx];
}

// s[i,j] = Ci + Dj + sum_h ab_h*|hq_ih + hkb_jh|, ab=0.05a, Dj=0.075(a.hkb_j)
// Ci per-row -> cancels in softmax -> dropped.
// khT4: [b][h4][j] uint4 = f16 pairs of h=8*h4..8*h4+7 (bias folded).
// hq2t: [rowblock][it 8][r 8][u 4] u32 f16 pairs (SMEM-friendly: per-it 128B).
// abd2: [h2] u32 pairs of 0.05a.
// vfrag: [b][kstep 32][nt 5][lane 64] uint4 — V in MFMA B-frag order;
//        nt=4 is the ones-column tile (col 64 == 1.0) for the softmax sum.

// ---------------- Kernel A: prep (blocks 0-127) + vpack (blocks 128-255) ------
__global__ __launch_bounds__(256) void prep_kernel(
    const float* __restrict__ qs, const float* __restrict__ ks,
    const float* __restrict__ vs,
    const float* __restrict__ W, const float* __restrict__ bias,
    const float* __restrict__ a,
    unsigned* __restrict__ hq2t, uint4* __restrict__ khT4,
    float* __restrict__ Dj, unsigned* __restrict__ abd2,
    uint4* __restrict__ vfrag) {
  __shared__ __align__(16) float wcomb[64][68];
  __shared__ __align__(16) float xin[64][68];
  const int blk = blockIdx.x;
  const int t = threadIdx.x;

  if (blk >= 128) {  // ---- vpack: V -> MFMA B-fragment f16 layout (5 tiles) ----
    const int unit = blk - 128;             // b = unit>>5, kstep = unit&31
    const int b = unit >> 5, kstep = unit & 31;
    const int lane = t & 63, ntile = t >> 6;
    const int j0 = kstep * 32 + (lane >> 4) * 8;
    const int d = ntile * 16 + (lane & 15);
    const float* vb = vs + b * 1024 * 64;
    unsigned pr[4];
#pragma unroll
    for (int i = 0; i < 4; ++i)
      pr[i] = pkrtz_u32(vb[(j0 + 2 * i) * 64 + d], vb[(j0 + 2 * i + 1) * 64 + d]);
    vfrag[((b * 32 + kstep) * 5 + ntile) * 64 + lane] =
        make_uint4(pr[0], pr[1], pr[2], pr[3]);
    if (t < 64) {  // ones-column tile (nt=4): col 64 == 1.0, rest 0
      unsigned v = ((t & 15) == 0) ? 0x3C003C00u : 0u;
      vfrag[((b * 32 + kstep) * 5 + 4) * 64 + t] = make_uint4(v, v, v, v);
    }
    return;
  }

  const bool qpart = blk < 64;
  const int r0 = (qpart ? blk : blk - 64) * 64;
  const float* src = qpart ? qs : ks;
  if (blk == 0 && t < 32)
    abd2[t] = pkrtz_u32(0.05f * a[2 * t], 0.05f * a[2 * t + 1]);
  for (int rep = 0; rep < 16; ++rep) {
    int e = rep * 256 + t;
    int row = e >> 6, col = e & 63;
    float wd = W[(128 + row) * 64 + col];
    float wm = qpart ? (W[row * 64 + col] + wd)
                     : (W[(64 + row) * 64 + col] - wd);
    wcomb[row][col] = wm;
    xin[row][col] = src[(r0 + row) * 64 + col];
  }
  __syncthreads();
  const int r = t >> 2;
  const int h0 = (t & 3) << 4;
  float acc[16];
#pragma unroll
  for (int k = 0; k < 16; ++k) acc[k] = 0.f;
#pragma unroll 8
  for (int d = 0; d < 64; ++d) {
    float xv = xin[r][d];
#pragma unroll
    for (int c = 0; c < 4; ++c) {
      float4 w4 = *(const float4*)&wcomb[d][h0 + (c << 2)];
      acc[c * 4 + 0] = fmaf(xv, w4.x, acc[c * 4 + 0]);
      acc[c * 4 + 1] = fmaf(xv, w4.y, acc[c * 4 + 1]);
      acc[c * 4 + 2] = fmaf(xv, w4.z, acc[c * 4 + 2]);
      acc[c * 4 + 3] = fmaf(xv, w4.w, acc[c * 4 + 3]);
    }
  }
  int grow = r0 + r;
  if (qpart) {
    unsigned pr[8];
#pragma unroll
    for (int i = 0; i < 8; ++i) pr[i] = pkrtz_u32(acc[2 * i], acc[2 * i + 1]);
    // hq2t[rowblock][it][r][u]: base = (grow>>3)*256 + (grow&7)*4
    const int base = (grow >> 3) * 256 + (grow & 7) * 4;
    const int it0 = (t & 3) * 2;
    *(uint4*)&hq2t[base + it0 * 32]       = make_uint4(pr[0], pr[1], pr[2], pr[3]);
    *(uint4*)&hq2t[base + (it0 + 1) * 32] = make_uint4(pr[4], pr[5], pr[6], pr[7]);
  } else {
    int bidx = grow >> 10;
    int j = grow & 1023;
    float val[16];
    float part = 0.f;
#pragma unroll
    for (int k = 0; k < 16; ++k) {
      val[k] = acc[k] + bias[h0 + k];
      part += a[h0 + k] * val[k];
    }
    part += __shfl_xor(part, 1);
    part += __shfl_xor(part, 2);
    if ((t & 3) == 0) Dj[bidx * 1024 + j] = 0.075f * part;
    unsigned pr[8];
#pragma unroll
    for (int i = 0; i < 8; ++i) pr[i] = pkrtz_u32(val[2 * i], val[2 * i + 1]);
    const int h4a = (t & 3) * 2;
    khT4[(bidx * 8 + h4a) * 1024 + j]     = make_uint4(pr[0], pr[1], pr[2], pr[3]);
    khT4[(bidx * 8 + h4a + 1) * 1024 + j] = make_uint4(pr[4], pr[5], pr[6], pr[7]);
  }
}

// ---------------- Kernel B: 8 rows x 1024 j; 8 waves; SMEM q; MFMA PV+sum ----
__global__ __launch_bounds__(512) void attn15_kernel(
    const uint4* __restrict__ vfrag,
    const unsigned* __restrict__ hq2t, const uint4* __restrict__ khT4,
    const float* __restrict__ Dj, const unsigned* __restrict__ abd2,
    float* __restrict__ out) {
  __shared__ __align__(16) unsigned p2u[8 * 520];   // p f16 pairs, row pad
  __shared__ __align__(16) float ob[64 * 64];       // [8w][8r][64d] 16KB
  __shared__ __align__(16) unsigned redmu[8 * 4];   // packed per-wave row maxes
  __shared__ __align__(16) float redl[8 * 8];       // [w][r] scaled l partials

  const int t = threadIdx.x;
  const int lane = t & 63;
  const int w = t >> 6;          // 0..7
  const int b = blockIdx.y;
  const int rowbase = blockIdx.x * 8;
  const int growbase = b * 1024 + rowbase;

  const uint4* kh_b = khT4 + (size_t)b * 8 * 1024;
  const uint4* vf_b = vfrag + (size_t)b * 32 * 5 * 64;
  const unsigned* qt = hq2t + (size_t)growbase * 32;  // [it][r][u], wave-uniform

  const int jloc = w * 128 + lane * 2;  // lane owns j = jloc, jloc+1
  float2 d2 = *(const float2*)(Dj + b * 1024 + jloc);

  float s[8][2];
#pragma unroll
  for (int r = 0; r < 8; ++r) { s[r][0] = 0.f; s[r][1] = 0.f; }

  // ---- scores: per h4-group (8 h); k dbuf in VGPRs; q/ab via s_load ----
  uint4 kc0 = kh_b[jloc], kc1 = kh_b[jloc + 1];
#pragma unroll 1
  for (int it = 0; it < 8; ++it) {
    const int nx = (it < 7) ? it + 1 : it;  // last iter: harmless reload
    uint4 kn0 = kh_b[nx * 1024 + jloc];
    uint4 kn1 = kh_b[nx * 1024 + jloc + 1];
    uint4 abq = *(const uint4*)(abd2 + it * 4);             // uniform -> s_load
    const unsigned abu[4] = {abq.x, abq.y, abq.z, abq.w};
    const unsigned kcu[2][4] = {{kc0.x, kc0.y, kc0.z, kc0.w},
                                {kc1.x, kc1.y, kc1.z, kc1.w}};
#pragma unroll
    for (int r = 0; r < 8; ++r) {
      uint4 qq = *(const uint4*)(qt + it * 32 + r * 4);     // uniform -> s_load
      const unsigned qu[4] = {qq.x, qq.y, qq.z, qq.w};
#pragma unroll
      for (int u = 0; u < 4; ++u) {
        h2v qh = u2h(qu[u]);
        h2v a2 = u2h(abu[u]);
        h2v x0 = habs2(qh + u2h(kcu[0][u]));
        s[r][0] = __builtin_amdgcn_fdot2(a2, x0, s[r][0], false);
        h2v x1 = habs2(qh + u2h(kcu[1][u]));
        s[r][1] = __builtin_amdgcn_fdot2(a2, x1, s[r][1], false);
      }
    }
    kc0 = kn0; kc1 = kn1;
  }
#pragma unroll
  for (int r = 0; r < 8; ++r) { s[r][0] += d2.x; s[r][1] += d2.y; }

  // ---- per-wave max via packed f16 butterfly (24 shuffles for all 8 rows) ----
  unsigned mp[4];
#pragma unroll
  for (int k = 0; k < 4; ++k)
    mp[k] = pkrtz_u32(fmaxf(s[2 * k][0], s[2 * k][1]),
                      fmaxf(s[2 * k + 1][0], s[2 * k + 1][1]));
#pragma unroll
  for (int off = 32; off >= 1; off >>= 1) {
#pragma unroll
    for (int k = 0; k < 4; ++k) mp[k] = pkmax_u(mp[k], __shfl_xor(mp[k], off));
  }
  if (lane == 0)
    *(uint4*)&redmu[w * 4] = make_uint4(mp[0], mp[1], mp[2], mp[3]);

  // ---- p = exp2(s - m_w), pack f16 to LDS (own wave's chunk only) ----
#pragma unroll
  for (int r = 0; r < 8; ++r) {
    float mwr = h2f(mp[r >> 1], r & 1);
    float p0 = __builtin_amdgcn_exp2f((s[r][0] - mwr) * LOG2E);
    float p1 = __builtin_amdgcn_exp2f((s[r][1] - mwr) * LOG2E);
    p2u[r * 520 + w * 64 + lane] = pkrtz_u32(p0, p1);
  }

  // ---- PV via MFMA (5 n-tiles; nt=4 is the ones column -> row sums) ----
  f32x4 acc[5];
#pragma unroll
  for (int nt = 0; nt < 5; ++nt) acc[nt] = (f32x4){0.f, 0.f, 0.f, 0.f};
  const int arow = (lane & 7) * 520;  // A rows 8-15 alias 0-7
  const int kgr = (lane >> 4) * 8;
#pragma unroll 2
  for (int ks = 0; ks < 4; ++ks) {
    const int j0 = w * 128 + ks * 32;
    uint4 au = *(const uint4*)&p2u[arow + ((j0 + kgr) >> 1)];
    f16x8 af; __builtin_memcpy(&af, &au, 16);
    const int gks = j0 >> 5;
#pragma unroll
    for (int nt = 0; nt < 5; ++nt) {
      uint4 bu = vf_b[(gks * 5 + nt) * 64 + lane];
      f16x8 bf; __builtin_memcpy(&bf, &bu, 16);
      acc[nt] = __builtin_amdgcn_mfma_f32_16x16x32_f16(af, bf, acc[nt], 0, 0, 0);
    }
  }
  __syncthreads();  // redmu from all waves visible

  // ---- global max (packed, redundant per wave), per-row rescale factors ----
  unsigned Mp[4];
  {
    uint4 v0 = *(const uint4*)&redmu[0];
    Mp[0] = v0.x; Mp[1] = v0.y; Mp[2] = v0.z; Mp[3] = v0.w;
#pragma unroll
    for (int wv = 1; wv < 8; ++wv) {
      uint4 vv = *(const uint4*)&redmu[wv * 4];
      Mp[0] = pkmax_u(Mp[0], vv.x); Mp[1] = pkmax_u(Mp[1], vv.y);
      Mp[2] = pkmax_u(Mp[2], vv.z); Mp[3] = pkmax_u(Mp[3], vv.w);
    }
  }
  const int rb = ((lane >> 4) & 1) * 4;  // this lane's 4 C rows (mod 8)
  float sc[4];
#pragma unroll
  for (int rg = 0; rg < 4; ++rg) {
    int r = rb + rg;
    float mwv = h2f(mp[r >> 1], r & 1);
    float Mv = h2f(Mp[r >> 1], r & 1);
    sc[rg] = __builtin_amdgcn_exp2f((mwv - Mv) * LOG2E);
  }

  // C rows 0-7 live in lanes 0-31: row = (lane>>4)*4 + reg
  if (lane < 32) {
#pragma unroll
    for (int nt = 0; nt < 4; ++nt)
#pragma unroll
      for (int rg = 0; rg < 4; ++rg)
        ob[(w * 8 + rb + rg) * 64 + nt * 16 + (lane & 15)] = acc[nt][rg] * sc[rg];
  }
  if ((lane & 47) == 0) {  // lanes 0,16 hold l (col 64) for rows rb..rb+3
    float4 lv;
    lv.x = acc[4][0] * sc[0]; lv.y = acc[4][1] * sc[1];
    lv.z = acc[4][2] * sc[2]; lv.w = acc[4][3] * sc[3];
    *(float4*)&redl[w * 8 + rb] = lv;
  }
  __syncthreads();

  // ---- epilogue: cross-wave sum + normalize + store ----
  {
    int r = t >> 6, d = t & 63;  // 512 threads cover 8 rows x 64 d
    float ax = 0.f, lt = 0.f;
#pragma unroll
    for (int wv = 0; wv < 8; ++wv) {
      ax += ob[(wv * 8 + r) * 64 + d];
      lt += redl[wv * 8 + r];
    }
    out[(growbase + r) * 64 + d] = ax / lt;
  }
}

extern "C" void kernel_launch(void* const* d_in, const int* in_sizes, int n_in,
                              void* d_out, int out_size, void* d_ws, size_t ws_size,
                              hipStream_t stream) {
  const float* qs = (const float*)d_in[0];
  const float* ks = (const float*)d_in[1];
  const float* vs = (const float*)d_in[2];
  const float* W  = (const float*)d_in[3];
  const float* bi = (const float*)d_in[4];
  const float* a  = (const float*)d_in[5];
  float* out = (float*)d_out;
  unsigned* hq2t  = (unsigned*)d_ws;                    // 512KB
  uint4*    khT4  = (uint4*)((char*)d_ws + 524288);     // 512KB
  float*    Dj    = (float*)((char*)d_ws + 1048576);    // 16KB
  unsigned* abd2  = (unsigned*)((char*)d_ws + 1064960); // 128B
  uint4*    vfrag = (uint4*)((char*)d_ws + 1065216);    // 640KB
  prep_kernel<<<256, 256, 0, stream>>>(qs, ks, vs, W, bi, a, hq2t, khT4, Dj,
                                       abd2, vfrag);
  attn15_kernel<<<dim3(128, 4), 512, 0, stream>>>(vfrag, hq2t, khT4, Dj, abd2, out);
}